// Round 1
// baseline (3396.407 us; speedup 1.0000x reference)
//
#include <hip/hip_runtime.h>

#define HH   100      // hidden
#define G4   400      // 4*H
#define BB   256      // batch
#define CC   9        // input channels
#define TT   1024     // timesteps
#define NCLS 6        // num classes

__device__ __forceinline__ float sigm(float x) {
    return __fdividef(1.0f, 1.0f + __expf(-x));
}
__device__ __forceinline__ float tanh_fast(float x) {
    // tanh(x) = 2*sigmoid(2x) - 1
    return 2.0f * sigm(2.0f * x) - 1.0f;
}

// ---------------- Layer 1: x[B,C,T] -> h1[B,T,H] ----------------
__global__ __launch_bounds__(448, 2)
void lstm_layer1(const float* __restrict__ x,     // [B,C,T]
                 const float* __restrict__ h0,    // [B,H]
                 const float* __restrict__ c0,    // [B,H]
                 const float* __restrict__ W_ih,  // [400,9]
                 const float* __restrict__ W_hh,  // [400,100]
                 const float* __restrict__ bias_g,// [400]
                 float* __restrict__ h1out)       // [B,T,H]
{
    const int b   = blockIdx.x;
    const int tid = threadIdx.x;

    __shared__ __align__(16) float xs[CC * TT];   // 36 KB
    __shared__ __align__(16) float hbuf[104];
    __shared__ float gates[G4];

    // stage x[b] into LDS (coalesced float4)
    {
        const float4* src = (const float4*)(x + (size_t)b * CC * TT);
        float4* dst = (float4*)xs;
        for (int i = tid; i < (CC * TT) / 4; i += blockDim.x) dst[i] = src[i];
    }
    if (tid < HH) hbuf[tid] = h0[b * HH + tid];
    float c_reg = (tid < HH) ? c0[b * HH + tid] : 0.0f;

    // register-resident weights for gate-row tid
    float w_ih[CC], w_hh[HH], bg = 0.0f;
    const bool isRow = (tid < G4);
    if (isRow) {
        #pragma unroll
        for (int j = 0; j < CC; ++j) w_ih[j] = W_ih[tid * CC + j];
        #pragma unroll
        for (int j = 0; j < HH; ++j) w_hh[j] = W_hh[tid * HH + j];
        bg = bias_g[tid];
    }
    const bool isG = (tid >= 2 * HH && tid < 3 * HH);   // tanh gate rows
    float* hout = h1out + (size_t)b * TT * HH;
    __syncthreads();

    for (int t = 0; t < TT; ++t) {
        if (isRow) {
            float a0 = bg, a1 = 0.f, a2 = 0.f, a3 = 0.f;
            #pragma unroll
            for (int c = 0; c < CC; ++c) a0 += w_ih[c] * xs[c * TT + t];
            const float4* h4 = (const float4*)hbuf;
            #pragma unroll
            for (int j = 0; j < HH / 4; ++j) {
                float4 hv = h4[j];
                a0 += w_hh[4 * j + 0] * hv.x;
                a1 += w_hh[4 * j + 1] * hv.y;
                a2 += w_hh[4 * j + 2] * hv.z;
                a3 += w_hh[4 * j + 3] * hv.w;
            }
            float raw = (a0 + a1) + (a2 + a3);
            float xv  = isG ? 2.0f * raw : raw;
            float s   = sigm(xv);
            gates[tid] = isG ? (2.0f * s - 1.0f) : s;
        }
        __syncthreads();
        if (tid < HH) {
            float gi = gates[tid];
            float gf = gates[tid + HH];
            float gg = gates[tid + 2 * HH];
            float go = gates[tid + 3 * HH];
            float cc = gf * c_reg + gi * gg;
            c_reg = cc;
            float hv = go * tanh_fast(cc);
            hbuf[tid] = hv;
            hout[t * HH + tid] = hv;
        }
        __syncthreads();
    }
}

// -------- Layer 2 + final FC: h1[B,T,H] -> out[B,NC] --------
__global__ __launch_bounds__(512, 2)
void lstm_layer2_fc(const float* __restrict__ h1,   // [B,T,H]
                    const float* __restrict__ h0,
                    const float* __restrict__ c0,
                    const float* __restrict__ W_ih, // [400,100]
                    const float* __restrict__ W_hh, // [400,100]
                    const float* __restrict__ bias_g,
                    const float* __restrict__ W_fc, // [6,100]
                    const float* __restrict__ b_fc, // [6]
                    float* __restrict__ out)        // [B,NC]
{
    const int b   = blockIdx.x;
    const int tid = threadIdx.x;

    __shared__ __align__(16) float h1buf[2][104];   // double-buffered h1_t
    __shared__ __align__(16) float h2buf[104];
    __shared__ float gates[G4];

    if (tid < HH) h2buf[tid] = h0[b * HH + tid];
    float c_reg = (tid < HH) ? c0[b * HH + tid] : 0.0f;

    float w_ih[HH], w_hh[HH], bg = 0.0f;
    const bool isRow = (tid < G4);
    if (isRow) {
        #pragma unroll
        for (int j = 0; j < HH; ++j) w_ih[j] = W_ih[tid * HH + j];
        #pragma unroll
        for (int j = 0; j < HH; ++j) w_hh[j] = W_hh[tid * HH + j];
        bg = bias_g[tid];
    }
    const bool isG = (tid >= 2 * HH && tid < 3 * HH);
    const bool isStage = (tid >= 448 && tid < 448 + HH / 4);  // wave 7: prefetchers
    const float* h1b = h1 + (size_t)b * TT * HH;

    // prologue: stage h1 at t=0
    if (isStage) {
        int i = tid - 448;
        ((float4*)h1buf[0])[i] = ((const float4*)h1b)[i];
    }
    __syncthreads();

    for (int t = 0; t < TT; ++t) {
        const int cur = t & 1;
        if (isRow) {
            float a0 = bg, a1 = 0.f, a2 = 0.f, a3 = 0.f;
            const float4* p = (const float4*)h1buf[cur];
            const float4* q = (const float4*)h2buf;
            #pragma unroll
            for (int j = 0; j < HH / 4; ++j) {
                float4 u = p[j];
                float4 v = q[j];
                a0 += w_ih[4 * j + 0] * u.x;
                a1 += w_ih[4 * j + 1] * u.y;
                a2 += w_ih[4 * j + 2] * u.z;
                a3 += w_ih[4 * j + 3] * u.w;
                a0 += w_hh[4 * j + 0] * v.x;
                a1 += w_hh[4 * j + 1] * v.y;
                a2 += w_hh[4 * j + 2] * v.z;
                a3 += w_hh[4 * j + 3] * v.w;
            }
            float raw = (a0 + a1) + (a2 + a3);
            float xv  = isG ? 2.0f * raw : raw;
            float s   = sigm(xv);
            gates[tid] = isG ? (2.0f * s - 1.0f) : s;
        } else if (isStage && (t + 1) < TT) {
            // prefetch next h1_t into the other buffer (hidden under FMA phase)
            int i = tid - 448;
            ((float4*)h1buf[cur ^ 1])[i] = ((const float4*)(h1b + (t + 1) * HH))[i];
        }
        __syncthreads();
        if (tid < HH) {
            float gi = gates[tid];
            float gf = gates[tid + HH];
            float gg = gates[tid + 2 * HH];
            float go = gates[tid + 3 * HH];
            float cc = gf * c_reg + gi * gg;
            c_reg = cc;
            h2buf[tid] = go * tanh_fast(cc);
        }
        __syncthreads();
    }

    // final FC on h2 at t = T-1
    if (tid < NCLS) {
        float acc = b_fc[tid];
        #pragma unroll 4
        for (int j = 0; j < HH; ++j) acc += W_fc[tid * HH + j] * h2buf[j];
        out[b * NCLS + tid] = acc;
    }
}

extern "C" void kernel_launch(void* const* d_in, const int* in_sizes, int n_in,
                              void* d_out, int out_size, void* d_ws, size_t ws_size,
                              hipStream_t stream) {
    const float* x     = (const float*)d_in[0];
    const float* h0_1  = (const float*)d_in[1];
    const float* c0_1  = (const float*)d_in[2];
    const float* h0_2  = (const float*)d_in[3];
    const float* c0_2  = (const float*)d_in[4];
    const float* W_ih1 = (const float*)d_in[5];
    const float* W_hh1 = (const float*)d_in[6];
    const float* b1    = (const float*)d_in[7];
    const float* W_ih2 = (const float*)d_in[8];
    const float* W_hh2 = (const float*)d_in[9];
    const float* b2    = (const float*)d_in[10];
    const float* W_fc  = (const float*)d_in[11];
    const float* b_fc  = (const float*)d_in[12];
    float* out = (float*)d_out;

    float* h1 = (float*)d_ws;   // [B,T,H] fp32 = 104.8 MB

    lstm_layer1<<<BB, 448, 0, stream>>>(x, h0_1, c0_1, W_ih1, W_hh1, b1, h1);
    lstm_layer2_fc<<<BB, 512, 0, stream>>>(h1, h0_2, c0_2, W_ih2, W_hh2, b2,
                                           W_fc, b_fc, out);
}

// Round 3
// 2344.742 us; speedup vs baseline: 1.4485x; 1.4485x over previous
//
#include <hip/hip_runtime.h>

#define HH   100      // hidden
#define G4   400      // 4*H
#define BB   256      // batch
#define CC   9        // input channels
#define TT   1024     // timesteps
#define NCLS 6        // num classes
#define XSTR 13       // padded stride for transposed x tile

__device__ __forceinline__ float sigm(float x) {
    return __fdividef(1.0f, 1.0f + __expf(-x));
}
__device__ __forceinline__ float tanh_fast(float x) {
    return 2.0f * sigm(2.0f * x) - 1.0f;
}
// wave-wide broadcast of lane l's value via readlane -> SGPR (no LDS pipe).
// REQUIRES: v was computed by ALL 64 lanes of the wave (no divergence upstream).
__device__ __forceinline__ float bcast(float v, int l) {
    return __int_as_float(__builtin_amdgcn_readlane(__float_as_int(v), l));
}

// ---------------- Layer 1: x[B,C,T] -> h1[B,T,H] ----------------
__global__ __launch_bounds__(448, 1)
void lstm_layer1(const float* __restrict__ x,     // [B,C,T]
                 const float* __restrict__ h0,    // [B,H]
                 const float* __restrict__ c0,    // [B,H]
                 const float* __restrict__ W_ih,  // [400,9]
                 const float* __restrict__ W_hh,  // [400,100]
                 const float* __restrict__ bias_g,// [400]
                 float* __restrict__ h1out)       // [B,T,H]
{
    const int b    = blockIdx.x;
    const int tid  = threadIdx.x;
    const int lane = tid & 63;

    __shared__ float xT[TT * XSTR + 64];   // transposed x: xT[t*13 + c]
    __shared__ float hb[128];              // h, padded + zeroed
    __shared__ float gates[448];           // 448 so the store is unconditional

    // stage x[b] transposed: [C,T] -> [T, stride 13]
    const float* xb = x + (size_t)b * CC * TT;
    for (int i = tid; i < CC * TT; i += 448) {
        int c  = i >> 10;        // i / 1024
        int tp = i & 1023;       // i % 1024
        xT[tp * XSTR + c] = xb[i];
    }
    if (tid < 128) hb[tid] = (tid < HH) ? h0[b * HH + tid] : 0.0f;
    float c_reg = (tid < HH) ? c0[b * HH + tid] : 0.0f;

    // register-resident weights; clamp row so ALL 448 threads hold valid data
    const int row = (tid < G4) ? tid : 0;
    float w_ih[CC], w_hh[HH], bg;
    #pragma unroll
    for (int j = 0; j < CC; ++j) w_ih[j] = W_ih[row * CC + j];
    #pragma unroll
    for (int j = 0; j < HH; ++j) w_hh[j] = W_hh[row * HH + j];
    bg = bias_g[row];
    const bool isG = (row >= 2 * HH && row < 3 * HH);   // tanh gate rows
    float* hout = h1out + (size_t)b * TT * HH;
    __syncthreads();

    for (int t = 0; t < TT; ++t) {
        // per-lane loads, executed by EVERY lane (no guard anywhere upstream
        // of the readlane consumers)
        float vx = xT[t * XSTR + lane];   // lanes >= 13 hold neighbors, unused
        float va = hb[lane];
        float vb = hb[64 + lane];         // broadcast only for j < 36
        asm volatile("" : "+v"(vx), "+v"(va), "+v"(vb));  // pin: no sinking

        float a0 = bg, a1 = 0.f, a2 = 0.f, a3 = 0.f;
        #pragma unroll
        for (int c = 0; c < CC; ++c) {
            float h_ = bcast(vx, c);
            if ((c & 3) == 0) a0 += h_ * w_ih[c];
            else if ((c & 3) == 1) a1 += h_ * w_ih[c];
            else if ((c & 3) == 2) a2 += h_ * w_ih[c];
            else a3 += h_ * w_ih[c];
        }
        #pragma unroll
        for (int j = 0; j < 64; ++j) {
            float h_ = bcast(va, j);
            if ((j & 3) == 0) a0 += h_ * w_hh[j];
            else if ((j & 3) == 1) a1 += h_ * w_hh[j];
            else if ((j & 3) == 2) a2 += h_ * w_hh[j];
            else a3 += h_ * w_hh[j];
        }
        #pragma unroll
        for (int j = 0; j < 36; ++j) {
            float h_ = bcast(vb, j);
            if ((j & 3) == 0) a0 += h_ * w_hh[64 + j];
            else if ((j & 3) == 1) a1 += h_ * w_hh[64 + j];
            else if ((j & 3) == 2) a2 += h_ * w_hh[64 + j];
            else a3 += h_ * w_hh[64 + j];
        }
        float raw = (a0 + a1) + (a2 + a3);
        float xv  = isG ? 2.0f * raw : raw;
        float s   = sigm(xv);
        gates[tid] = isG ? (2.0f * s - 1.0f) : s;   // unconditional store

        __syncthreads();
        if (tid < HH) {
            float gi = gates[tid];
            float gf = gates[tid + HH];
            float gg = gates[tid + 2 * HH];
            float go = gates[tid + 3 * HH];
            float cc = gf * c_reg + gi * gg;
            c_reg = cc;
            float hv = go * tanh_fast(cc);
            hb[tid] = hv;
            hout[t * HH + tid] = hv;
        }
        __syncthreads();
    }
}

// -------- Layer 2 + final FC: h1[B,T,H] -> out[B,NC] --------
__global__ __launch_bounds__(512, 1)
void lstm_layer2_fc(const float* __restrict__ h1,   // [B,T,H]
                    const float* __restrict__ h0,
                    const float* __restrict__ c0,
                    const float* __restrict__ W_ih, // [400,100]
                    const float* __restrict__ W_hh, // [400,100]
                    const float* __restrict__ bias_g,
                    const float* __restrict__ W_fc, // [6,100]
                    const float* __restrict__ b_fc, // [6]
                    float* __restrict__ out)        // [B,NC]
{
    const int b    = blockIdx.x;
    const int tid  = threadIdx.x;
    const int lane = tid & 63;

    __shared__ float h1buf[2][128];   // double-buffered h1_t, padded + zeroed
    __shared__ float h2b[128];
    __shared__ float gates[448];

    if (tid < 128) {
        h2b[tid] = (tid < HH) ? h0[b * HH + tid] : 0.0f;
        h1buf[0][tid] = 0.0f;
        h1buf[1][tid] = 0.0f;
    }
    float c_reg = (tid < HH) ? c0[b * HH + tid] : 0.0f;

    const int row = (tid < G4) ? tid : 0;
    float w_ih[HH], w_hh[HH], bg;
    #pragma unroll
    for (int j = 0; j < HH; ++j) w_ih[j] = W_ih[row * HH + j];
    #pragma unroll
    for (int j = 0; j < HH; ++j) w_hh[j] = W_hh[row * HH + j];
    bg = bias_g[row];
    const bool isG = (row >= 2 * HH && row < 3 * HH);
    const float* h1b = h1 + (size_t)b * TT * HH;
    __syncthreads();   // h1buf zeroed before anyone writes/reads it

    // prologue: stage h1 at t=0 (wave 7 threads)
    if (tid >= 448 && tid < 448 + HH / 4) {
        int i = tid - 448;
        ((float4*)h1buf[0])[i] = ((const float4*)h1b)[i];
    }
    __syncthreads();

    for (int t = 0; t < TT; ++t) {
        const int cur = t & 1;
        if (tid < 448) {   // waves 0..6: wave-uniform guard, all 64 lanes active
            float va = h1buf[cur][lane];
            float vb = h1buf[cur][64 + lane];  // broadcast only for j < 36
            float vc = h2b[lane];
            float vd = h2b[64 + lane];
            asm volatile("" : "+v"(va), "+v"(vb), "+v"(vc), "+v"(vd));

            float a0 = bg, a1 = 0.f, a2 = 0.f, a3 = 0.f;
            #pragma unroll
            for (int j = 0; j < 64; ++j) {
                float h_ = bcast(va, j);
                if ((j & 3) == 0) a0 += h_ * w_ih[j];
                else if ((j & 3) == 1) a1 += h_ * w_ih[j];
                else if ((j & 3) == 2) a2 += h_ * w_ih[j];
                else a3 += h_ * w_ih[j];
            }
            #pragma unroll
            for (int j = 0; j < 36; ++j) {
                float h_ = bcast(vb, j);
                if ((j & 3) == 0) a0 += h_ * w_ih[64 + j];
                else if ((j & 3) == 1) a1 += h_ * w_ih[64 + j];
                else if ((j & 3) == 2) a2 += h_ * w_ih[64 + j];
                else a3 += h_ * w_ih[64 + j];
            }
            #pragma unroll
            for (int j = 0; j < 64; ++j) {
                float h_ = bcast(vc, j);
                if ((j & 3) == 0) a0 += h_ * w_hh[j];
                else if ((j & 3) == 1) a1 += h_ * w_hh[j];
                else if ((j & 3) == 2) a2 += h_ * w_hh[j];
                else a3 += h_ * w_hh[j];
            }
            #pragma unroll
            for (int j = 0; j < 36; ++j) {
                float h_ = bcast(vd, j);
                if ((j & 3) == 0) a0 += h_ * w_hh[64 + j];
                else if ((j & 3) == 1) a1 += h_ * w_hh[64 + j];
                else if ((j & 3) == 2) a2 += h_ * w_hh[64 + j];
                else a3 += h_ * w_hh[64 + j];
            }
            float raw = (a0 + a1) + (a2 + a3);
            float xv  = isG ? 2.0f * raw : raw;
            float s   = sigm(xv);
            gates[tid] = isG ? (2.0f * s - 1.0f) : s;   // unconditional in-wave
        } else if ((t + 1) < TT && tid < 448 + HH / 4) {
            // wave 7: prefetch next h1_t into the other buffer
            int i = tid - 448;
            ((float4*)h1buf[cur ^ 1])[i] = ((const float4*)(h1b + (t + 1) * HH))[i];
        }
        __syncthreads();
        if (tid < HH) {
            float gi = gates[tid];
            float gf = gates[tid + HH];
            float gg = gates[tid + 2 * HH];
            float go = gates[tid + 3 * HH];
            float cc = gf * c_reg + gi * gg;
            c_reg = cc;
            h2b[tid] = go * tanh_fast(cc);
        }
        __syncthreads();
    }

    // final FC on h2 at t = T-1
    if (tid < NCLS) {
        float acc = b_fc[tid];
        #pragma unroll 4
        for (int j = 0; j < HH; ++j) acc += W_fc[tid * HH + j] * h2b[j];
        out[b * NCLS + tid] = acc;
    }
}

extern "C" void kernel_launch(void* const* d_in, const int* in_sizes, int n_in,
                              void* d_out, int out_size, void* d_ws, size_t ws_size,
                              hipStream_t stream) {
    const float* x     = (const float*)d_in[0];
    const float* h0_1  = (const float*)d_in[1];
    const float* c0_1  = (const float*)d_in[2];
    const float* h0_2  = (const float*)d_in[3];
    const float* c0_2  = (const float*)d_in[4];
    const float* W_ih1 = (const float*)d_in[5];
    const float* W_hh1 = (const float*)d_in[6];
    const float* b1    = (const float*)d_in[7];
    const float* W_ih2 = (const float*)d_in[8];
    const float* W_hh2 = (const float*)d_in[9];
    const float* b2    = (const float*)d_in[10];
    const float* W_fc  = (const float*)d_in[11];
    const float* b_fc  = (const float*)d_in[12];
    float* out = (float*)d_out;

    float* h1 = (float*)d_ws;   // [B,T,H] fp32 = 104.8 MB

    lstm_layer1<<<BB, 448, 0, stream>>>(x, h0_1, c0_1, W_ih1, W_hh1, b1, h1);
    lstm_layer2_fc<<<BB, 512, 0, stream>>>(h1, h0_2, c0_2, W_ih2, W_hh2, b2,
                                           W_fc, b_fc, out);
}